// Round 1
// baseline (257.509 us; speedup 1.0000x reference)
//
#include <hip/hip_runtime.h>

// out[b, t, n, :] = x[b, (t - shift[n]) % 16, n, :]
// x: (B=16, T=16, N=196, c=768) fp32, contiguous.
//
// shift[n] closed form (m=1): w=n%7, h=n/7, a=w%3, b=h%3:
//   (0,0)->-4 (0,1)->1 (0,2)->2
//   (1,0)->-1 (1,1)-> (n==8 ? 0 : -1)   // sticky inv_state: only i=8 sees inv==0
//   (1,2)->3  (2,0)->-2 (2,1)->-3 (2,2)->4
//
// One block per (n, t, b) row; 192 threads x float4 = 768 floats = one channel row.
// Fully coalesced 16B/lane loads+stores; shift is wave-uniform (n = blockIdx.x).

__global__ __launch_bounds__(192) void Rand2dPatchShift_kernel(
        const float4* __restrict__ x, float4* __restrict__ out) {
    const int n = blockIdx.x;   // 0..195
    const int t = blockIdx.y;   // 0..15
    const int b = blockIdx.z;   // 0..15

    const int w  = n % 7;
    const int h  = n / 7;
    const int a3 = w % 3;
    const int b3 = h % 3;

    int s;
    if (a3 == 0)      s = (b3 == 0) ? -4 : (b3 == 1 ? 1 : 2);
    else if (a3 == 1) s = (b3 == 0) ? -1 : (b3 == 1 ? ((n == 8) ? 0 : -1) : 3);
    else              s = (b3 == 0) ? -2 : (b3 == 1 ? -3 : 4);

    const int tsrc = (t - s + 16) & 15;

    // row length in float4: 768/4 = 192
    const long long dst = (((long long)b * 16 + t   ) * 196 + n) * 192 + threadIdx.x;
    const long long src = (((long long)b * 16 + tsrc) * 196 + n) * 192 + threadIdx.x;
    out[dst] = x[src];
}

extern "C" void kernel_launch(void* const* d_in, const int* in_sizes, int n_in,
                              void* d_out, int out_size, void* d_ws, size_t ws_size,
                              hipStream_t stream) {
    const float4* x = (const float4*)d_in[0];
    float4* out = (float4*)d_out;

    dim3 grid(196, 16, 16);   // (n, t, b)
    dim3 block(192);          // 3 waves, one float4 per thread
    Rand2dPatchShift_kernel<<<grid, block, 0, stream>>>(x, out);
}

// Round 3
// 251.281 us; speedup vs baseline: 1.0248x; 1.0248x over previous
//
#include <hip/hip_runtime.h>

// out[b, t, n, :] = x[b, (t - shift[n]) % 16, n, :]
// x: (B=16, T=16, N=196, c=768) fp32, contiguous.
//
// shift[n] closed form (m=1): w=n%7, h=n/7, a=w%3, b=h%3:
//   (0,0)->-4 (0,1)->1 (0,2)->2
//   (1,0)->-1 (1,1)-> (n==8 ? 0 : -1)   // sticky inv_state: only i=8 sees inv==0
//   (1,2)->3  (2,0)->-2 (2,1)->-3 (2,2)->4
//
// R2: same as R1 but with native Clang vector type (ext_vector_type) so the
// nontemporal builtins compile. One block per (n, b); each thread copies one
// float4 lane for all 16 t values (unrolled) -> 16 loads in flight per lane.

typedef float f4 __attribute__((ext_vector_type(4)));

__global__ __launch_bounds__(192) void Rand2dPatchShift_kernel(
        const f4* __restrict__ x, f4* __restrict__ out) {
    const int n = blockIdx.x;   // 0..195
    const int b = blockIdx.y;   // 0..15

    const int w  = n % 7;
    const int h  = n / 7;
    const int a3 = w % 3;
    const int b3 = h % 3;

    int s;
    if (a3 == 0)      s = (b3 == 0) ? -4 : (b3 == 1 ? 1 : 2);
    else if (a3 == 1) s = (b3 == 0) ? -1 : (b3 == 1 ? ((n == 8) ? 0 : -1) : 3);
    else              s = (b3 == 0) ? -2 : (b3 == 1 ? -3 : 4);

    // base of (b, t=0, n, :) in float4 units; row stride over t is 196*192
    const long long base = ((long long)b * 16 * 196 + n) * 192 + threadIdx.x;
    const long long tstride = 196 * 192;

    f4 v[16];
#pragma unroll
    for (int t = 0; t < 16; ++t) {
        const int tsrc = (t - s + 16) & 15;
        v[t] = __builtin_nontemporal_load(&x[base + (long long)tsrc * tstride]);
    }
#pragma unroll
    for (int t = 0; t < 16; ++t) {
        __builtin_nontemporal_store(v[t], &out[base + (long long)t * tstride]);
    }
}

extern "C" void kernel_launch(void* const* d_in, const int* in_sizes, int n_in,
                              void* d_out, int out_size, void* d_ws, size_t ws_size,
                              hipStream_t stream) {
    const f4* x = (const f4*)d_in[0];
    f4* out = (f4*)d_out;

    dim3 grid(196, 16);   // (n, b)
    dim3 block(192);      // 3 waves, one float4 lane per thread, 16 t's each
    Rand2dPatchShift_kernel<<<grid, block, 0, stream>>>(x, out);
}